// Round 9
// baseline (90.817 us; speedup 1.0000x reference)
//
#include <hip/hip_runtime.h>

// Product quantizer: N=16384, D=1024, M=64 subspaces, K=256 codes, d=16.
// Scores s = x·c - 0.5||c||^2 (argmax == argmin dist) via split-bf16 16x16x32 MFMA:
//   A = [ch | cl] (codebook hi/lo), B1 = [xh|xh], B2 = [xl|xl]
//   -> acc = A·B1 + A·B2 = full (ch+cl)·(xh+xl)   (k-slot pairing, layout-independent).
// LDS A-frags stored LANE-PERMUTED: position kt*64 + l holds the frag lane l reads
// -> ds_read_b128 is 64 consecutive 16B chunks, zero bank conflicts (R8 had the
// [col*4+ds] order: 64B col-stride -> banks {0,16} -> ~8-way conflict = 92us floor).
// 64 rows (4 sub-tiles) per kt pass share each A/h read. Tracking packs code into
// low-8 mantissa bits; best/sec pure max/min chains. Masked top-2 gap < MARGIN ->
// LDS-batched flag -> exact f64 refine (first-min tie-break).
// NOTE: __launch_bounds__ min-waves MUST stay <=2: (256,6) caps VGPR at 40 and
// spills catastrophically (R6: WRITE 236MB, FETCH 720MB, 3.2x slower).

#define DIMS   1024
#define MSUB   64
#define KCODE  256
#define DSUB   16
#define FLCAP  128

static constexpr float MARGIN = 2e-3f;

typedef __attribute__((ext_vector_type(8))) short s16x8;
typedef __attribute__((ext_vector_type(4))) float f32x4;
typedef __attribute__((ext_vector_type(4))) unsigned int u32x4;

static __device__ __forceinline__ f32x4 mfma32(s16x8 a, s16x8 b, f32x4 c) {
    return __builtin_amdgcn_mfma_f32_16x16x32_bf16(a, b, c, 0, 0, 0);
}

// Truncation split of 4 floats into duplicated bf16 frags [xh|xh], [xl|xl].
static __device__ __forceinline__ void mk_bfrags(float4 xv, s16x8& B1, s16x8& B2) {
    unsigned u0 = __float_as_uint(xv.x), u1 = __float_as_uint(xv.y);
    unsigned u2 = __float_as_uint(xv.z), u3 = __float_as_uint(xv.w);
    unsigned h01 = (u1 & 0xFFFF0000u) | (u0 >> 16);
    unsigned h23 = (u3 & 0xFFFF0000u) | (u2 >> 16);
    float l0 = xv.x - __uint_as_float(u0 & 0xFFFF0000u);
    float l1 = xv.y - __uint_as_float(u1 & 0xFFFF0000u);
    float l2 = xv.z - __uint_as_float(u2 & 0xFFFF0000u);
    float l3 = xv.w - __uint_as_float(u3 & 0xFFFF0000u);
    unsigned l01 = (__float_as_uint(l1) & 0xFFFF0000u) | (__float_as_uint(l0) >> 16);
    unsigned l23 = (__float_as_uint(l3) & 0xFFFF0000u) | (__float_as_uint(l2) >> 16);
    B1 = __builtin_bit_cast(s16x8, (u32x4){h01, h23, h01, h23});
    B2 = __builtin_bit_cast(s16x8, (u32x4){l01, l23, l01, l23});
}

// Block = 256 threads = 4 waves, one m per block, 512 rows/block (wave: 128 rows =
// 2 passes of 64 rows = 4 sub-tiles). Grid 2048 = 64 m x 32 row-groups, XCD-grouped.
__global__ __launch_bounds__(256, 2) void pq_main(
    const float* __restrict__ embeds,
    const float* __restrict__ codebooks,
    float* __restrict__ out,
    unsigned* __restrict__ flag_cnt,
    unsigned* __restrict__ flag_list,
    unsigned flag_cap)
{
    __shared__ u32x4 chcl[16 * 64];       // 16KB: A-frags, position kt*64 + lane
    __shared__ float cnorm[KCODE];        // 1KB: -0.5*||c||^2, code-major
    __shared__ unsigned fl_buf[FLCAP];
    __shared__ unsigned fl_cnt, fl_base;

    const int tid = threadIdx.x;
    const int bid = blockIdx.x;
    const int m   = (bid >> 3) & 63;                  // subspace
    const int g   = (bid & 7) | ((bid >> 9) << 3);    // row-group (0..31), XCD-grouped
    const float* cbm = codebooks + (size_t)m * (KCODE * DSUB);

    if (tid == 0) fl_cnt = 0;

    // ---- Stage codebook[m]: thread tid owns code tid (contiguous 16KB read).
    // Lane-permuted store: code kt*16+c, dims d*4.. -> position kt*64 + d*16 + c,
    // so reader lane l (col=l&15, ds=l>>4) finds its frag at kt*64 + l.
    {
        const float4* src = (const float4*)(cbm + tid * DSUB);
        float c[16];
        #pragma unroll
        for (int q = 0; q < 4; ++q) {
            float4 v = src[q];
            c[4*q+0] = v.x; c[4*q+1] = v.y; c[4*q+2] = v.z; c[4*q+3] = v.w;
        }
        float ss = 0.f;
        #pragma unroll
        for (int j = 0; j < 16; ++j) ss = fmaf(c[j], c[j], ss);
        cnorm[tid] = -0.5f * ss;
        #pragma unroll
        for (int d = 0; d < 4; ++d) {
            unsigned uc0 = __float_as_uint(c[4*d+0]), uc1 = __float_as_uint(c[4*d+1]);
            unsigned uc2 = __float_as_uint(c[4*d+2]), uc3 = __float_as_uint(c[4*d+3]);
            unsigned hc01 = (uc1 & 0xFFFF0000u) | (uc0 >> 16);
            unsigned hc23 = (uc3 & 0xFFFF0000u) | (uc2 >> 16);
            float lc0 = c[4*d+0] - __uint_as_float(uc0 & 0xFFFF0000u);
            float lc1 = c[4*d+1] - __uint_as_float(uc1 & 0xFFFF0000u);
            float lc2 = c[4*d+2] - __uint_as_float(uc2 & 0xFFFF0000u);
            float lc3 = c[4*d+3] - __uint_as_float(uc3 & 0xFFFF0000u);
            unsigned lc01 = (__float_as_uint(lc1) & 0xFFFF0000u) | (__float_as_uint(lc0) >> 16);
            unsigned lc23 = (__float_as_uint(lc3) & 0xFFFF0000u) | (__float_as_uint(lc2) >> 16);
            chcl[(tid >> 4) * 64 + d * 16 + (tid & 15)] = (u32x4){hc01, hc23, lc01, lc23};
        }
    }
    __syncthreads();

    const int w   = tid >> 6;
    const int l   = tid & 63;
    const int col = l & 15;       // x-row within 16-row sub-tile (MFMA B/C col)
    const int ds  = l >> 4;       // k-segment / C row-group (codes)
    const int n0  = (g << 9) + (w << 7);   // 128 rows per wave

    const float* xp = embeds + (size_t)(n0 + col) * DIMS + m * DSUB + ds * 4;
    float*       op = out    + (size_t)(n0 + col) * DIMS + m * DSUB + ds * 4;
    const u32x4* av  = chcl + l;                       // + kt*64 per k-tile
    const f32x4* hvp = (const f32x4*)cnorm + ds;       // + kt*4 per k-tile
    const unsigned MSK = 0xFFFFFF00u;
    const size_t RS = 16 * DIMS;                       // 16-row stride

    float4 xv0 = *(const float4*)(xp);
    float4 xv1 = *(const float4*)(xp + RS);
    float4 xv2 = *(const float4*)(xp + 2 * RS);
    float4 xv3 = *(const float4*)(xp + 3 * RS);

    #pragma unroll 1
    for (int p = 0; p < 2; ++p) {
        s16x8 B1_0, B2_0, B1_1, B2_1, B1_2, B2_2, B1_3, B2_3;
        mk_bfrags(xv0, B1_0, B2_0);
        mk_bfrags(xv1, B1_1, B2_1);
        mk_bfrags(xv2, B1_2, B2_2);
        mk_bfrags(xv3, B1_3, B2_3);
        if (p == 0) {
            xv0 = *(const float4*)(xp + 4 * RS);
            xv1 = *(const float4*)(xp + 5 * RS);
            xv2 = *(const float4*)(xp + 6 * RS);
            xv3 = *(const float4*)(xp + 7 * RS);
        }

        float b0 = -3e38f, s0 = -3e38f, b1 = -3e38f, s1 = -3e38f;
        float b2 = -3e38f, s2 = -3e38f, b3 = -3e38f, s3 = -3e38f;

        #pragma unroll
        for (int kt = 0; kt < 16; ++kt) {
            s16x8 A = __builtin_bit_cast(s16x8, av[kt * 64]);  // consecutive b128
            f32x4 h = hvp[kt * 4];                             // broadcast b128
            f32x4 a0 = mfma32(A, B1_0, h); a0 = mfma32(A, B2_0, a0);
            f32x4 a1 = mfma32(A, B1_1, h); a1 = mfma32(A, B2_1, a1);
            f32x4 a2 = mfma32(A, B1_2, h); a2 = mfma32(A, B2_2, a2);
            f32x4 a3 = mfma32(A, B1_3, h); a3 = mfma32(A, B2_3, a3);
            #pragma unroll
            for (int r = 0; r < 4; ++r) {
                const unsigned code = (unsigned)(kt * 16 + r);
                float p0 = __uint_as_float((__float_as_uint(a0[r]) & MSK) | code);
                s0 = fmaxf(s0, fminf(p0, b0)); b0 = fmaxf(b0, p0);
                float p1 = __uint_as_float((__float_as_uint(a1[r]) & MSK) | code);
                s1 = fmaxf(s1, fminf(p1, b1)); b1 = fmaxf(b1, p1);
                float p2 = __uint_as_float((__float_as_uint(a2[r]) & MSK) | code);
                s2 = fmaxf(s2, fminf(p2, b2)); b2 = fmaxf(b2, p2);
                float p3 = __uint_as_float((__float_as_uint(a3[r]) & MSK) | code);
                s3 = fmaxf(s3, fminf(p3, b3)); b3 = fmaxf(b3, p3);
            }
        }

        // Fold the lane-constant ds*4 into the packed code (low byte <= 243+12).
        const unsigned d4 = (unsigned)(ds * 4);
        b0 = __uint_as_float(__float_as_uint(b0) + d4);
        s0 = __uint_as_float(__float_as_uint(s0) + d4);
        b1 = __uint_as_float(__float_as_uint(b1) + d4);
        s1 = __uint_as_float(__float_as_uint(s1) + d4);
        b2 = __uint_as_float(__float_as_uint(b2) + d4);
        s2 = __uint_as_float(__float_as_uint(s2) + d4);
        b3 = __uint_as_float(__float_as_uint(b3) + d4);
        s3 = __uint_as_float(__float_as_uint(s3) + d4);

        // Combine the 4 code-partitions (xor 16, 32): all lanes of a col agree.
        #pragma unroll
        for (int msk = 16; msk <= 32; msk <<= 1) {
            float o;
            o = __shfl_xor(b0, msk); float q0 = __shfl_xor(s0, msk);
            s0 = fmaxf(fmaxf(s0, q0), fminf(b0, o)); b0 = fmaxf(b0, o);
            o = __shfl_xor(b1, msk); float q1 = __shfl_xor(s1, msk);
            s1 = fmaxf(fmaxf(s1, q1), fminf(b1, o)); b1 = fmaxf(b1, o);
            o = __shfl_xor(b2, msk); float q2 = __shfl_xor(s2, msk);
            s2 = fmaxf(fmaxf(s2, q2), fminf(b2, o)); b2 = fmaxf(b2, o);
            o = __shfl_xor(b3, msk); float q3 = __shfl_xor(s3, msk);
            s3 = fmaxf(fmaxf(s3, q3), fminf(b3, o)); b3 = fmaxf(b3, o);
        }

        const int i0 = (int)(__float_as_uint(b0) & 255u);
        const int i1 = (int)(__float_as_uint(b1) & 255u);
        const int i2 = (int)(__float_as_uint(b2) & 255u);
        const int i3 = (int)(__float_as_uint(b3) & 255u);

        // Exact f32 codeword gathers (L1-hot) + 64B-chunk stores.
        float* obase = op + (size_t)p * 4 * RS;
        *(float4*)(obase)          = *(const float4*)(cbm + (size_t)i0 * DSUB + ds * 4);
        *(float4*)(obase + RS)     = *(const float4*)(cbm + (size_t)i1 * DSUB + ds * 4);
        *(float4*)(obase + 2 * RS) = *(const float4*)(cbm + (size_t)i2 * DSUB + ds * 4);
        *(float4*)(obase + 3 * RS) = *(const float4*)(cbm + (size_t)i3 * DSUB + ds * 4);

        if (ds == 0) {
            const int nb = n0 + p * 64 + col;
            float bb[4] = {b0, b1, b2, b3}, sb[4] = {s0, s1, s2, s3};
            #pragma unroll
            for (int s = 0; s < 4; ++s) {
                float gap = __uint_as_float(__float_as_uint(bb[s]) & MSK) -
                            __uint_as_float(__float_as_uint(sb[s]) & MSK);
                if (gap < MARGIN) {
                    unsigned ent = (unsigned)((nb + s * 16) * 64 + m);
                    unsigned q = atomicAdd(&fl_cnt, 1u);
                    if (q < FLCAP) fl_buf[q] = ent;
                    else { unsigned qq = atomicAdd(flag_cnt, 1u);
                           if (qq < flag_cap) flag_list[qq] = ent; }
                }
            }
        }
    }

    // ---- One global atomic per block; coalesced flag flush ----
    __syncthreads();
    unsigned c = fl_cnt; if (c > FLCAP) c = FLCAP;
    if (tid == 0) fl_base = atomicAdd(flag_cnt, c);
    __syncthreads();
    const unsigned base = fl_base;
    for (unsigned i = tid; i < c; i += 256) {
        unsigned q = base + i;
        if (q < flag_cap) flag_list[q] = fl_buf[i];
    }
}

// One wave per flagged (n,m): exact f64 distances, first-min tie-break.
__global__ __launch_bounds__(256) void pq_refine(
    const float* __restrict__ embeds,
    const float* __restrict__ codebooks,
    float* __restrict__ out,
    const unsigned* __restrict__ flag_cnt,
    const unsigned* __restrict__ flag_list,
    unsigned flag_cap)
{
    unsigned cnt = *flag_cnt;
    if (cnt > flag_cap) cnt = flag_cap;
    const int l = threadIdx.x & 63;
    const unsigned wid = (blockIdx.x << 2) | (unsigned)(threadIdx.x >> 6);
    const unsigned nw  = gridDim.x << 2;

    for (unsigned i = wid; i < cnt; i += nw) {
        const unsigned e = flag_list[i];
        const int n = (int)(e >> 6), m = (int)(e & 63u);
        const float* xrow = embeds + (size_t)n * DIMS + m * DSUB;
        double xd[DSUB];
        #pragma unroll
        for (int dd = 0; dd < DSUB; ++dd) xd[dd] = (double)xrow[dd];
        const float* cbm = codebooks + (size_t)m * (KCODE * DSUB);

        double bd = 1e300;
        int bi = 0;
        #pragma unroll 1
        for (int cc = 0; cc < 4; ++cc) {
            const int c = l * 4 + cc;                 // lane-local ascending
            const float* cp = cbm + c * DSUB;
            double s = 0.0;
            #pragma unroll
            for (int dd = 0; dd < DSUB; ++dd) {
                double diff = xd[dd] - (double)cp[dd];
                s = fma(diff, diff, s);
            }
            if (s < bd) { bd = s; bi = c; }
        }
        #pragma unroll
        for (int msk = 1; msk <= 32; msk <<= 1) {
            double ob = __shfl_xor(bd, msk);
            int   oi  = __shfl_xor(bi, msk);
            if (ob < bd || (ob == bd && oi < bi)) { bd = ob; bi = oi; }
        }
        if (l < DSUB) out[(size_t)n * DIMS + m * DSUB + l] = cbm[bi * DSUB + l];
    }
}

extern "C" void kernel_launch(void* const* d_in, const int* in_sizes, int n_in,
                              void* d_out, int out_size, void* d_ws, size_t ws_size,
                              hipStream_t stream)
{
    const float* embeds    = (const float*)d_in[0];
    const float* codebooks = (const float*)d_in[1];
    float* out = (float*)d_out;

    unsigned* flag_cnt  = (unsigned*)d_ws;
    unsigned* flag_list = (unsigned*)d_ws + 4;   // 16B offset
    unsigned flag_cap = 0;
    if (ws_size >= 32) {
        size_t cap = (ws_size - 16) / sizeof(unsigned);
        flag_cap = (cap > 0x7FFFFFFFull) ? 0x7FFFFFFFu : (unsigned)cap;
    }

    hipMemsetAsync(d_ws, 0, 16, stream);

    pq_main<<<dim3(2048), dim3(256), 0, stream>>>(
        embeds, codebooks, out, flag_cnt, flag_list, flag_cap);

    pq_refine<<<dim3(256), dim3(256), 0, stream>>>(
        embeds, codebooks, out, flag_cnt, flag_list, flag_cap);
}